// Round 22
// baseline (908.239 us; speedup 1.0000x reference)
//
#include <hip/hip_runtime.h>
#include <hip/hip_bf16.h>
#include <cstdint>

// out[M,N] = x[M,K] @ weight[N,K]^T, fp32 device buffers.
// R22: OVERLAPPED cvt+GEMM. TWO plain dispatches (pure-arithmetic selection):
//   1) reset_cnt16: zero 16 epoch counters in ws tail (ws poisoned pre-timing)
//   2) persist_cvt_gemm<<<256,512>>>, 1 block/CU:
//      - cvt split into 10 "rounds" of 256 chunks (chunk = 32KB bf16 tile of
//        one (panel256, kt64)), kt-MAJOR order: early-K chunks for all panels
//        convert first. LDS-FREE cvt (coalesced 256B-run reads, 8x128B-run
//        writes) so the GEMM keeps its full 128KB LDS.
//      - rounds 0-1 before GEMM; rounds 2-9 interleaved between KSTEPs of
//        loop iterations 1-4. GEMM inner loop = R14-EXACT publish-once KSTEP.
//      - sync: per-round counters cnt[j] (threadfence release + release-add);
//        consumers check every 8 tiles (relaxed poll + one acquire).
//      - vmcnt ledger: CVT_ROUND drains vmcnt(0) between KSTEPs (early-
//        retires staging loads; KSTEP's vmcnt(2) is a <=-wait -> correct).
// Deadlock audit: waits at pair-iter tt need rounds done by all blocks at
// their tt'<=4; only the startup-gate (rounds 0-1, unconditional) precedes
// any wait -> monotone marching, no cycles.

typedef __bf16 bf16x8 __attribute__((ext_vector_type(8)));
typedef float f32x4 __attribute__((ext_vector_type(4)));
typedef unsigned short u16x8 __attribute__((ext_vector_type(8)));

#define GAS __attribute__((address_space(1)))
#define LAS __attribute__((address_space(3)))
#define ASYNC16(gsrc, ldst)                                                  \
    __builtin_amdgcn_global_load_lds((GAS uint32_t*)(const void*)(gsrc),     \
                                     (LAS uint32_t*)(ldst), 16, 0, 0)

__device__ inline unsigned short f2bf(float f) {
    __hip_bfloat16 h = __float2bfloat16(f);  // RNE
    return *reinterpret_cast<unsigned short*>(&h);
}

__global__ void reset_cnt16(unsigned int* cnt) {
    for (int i = 0; i < 16; ++i) atomicExch(&cnt[i], 0u);
}

// One cvt round: block bid converts chunk c' = j*256 + bid (kt-major:
// kt = c'/40, panel = c'%40; panels 0..7 = A tiles, 8..39 = B tiles).
// Reads coalesced (8 thr x 32B per 256B row-segment); writes are 8x16B per
// thread forming 128B contiguous runs across lanes (full 64B lines).
__device__ __forceinline__ void cvt_round(
    int j, const float* __restrict__ A32, const float* __restrict__ B32,
    unsigned short* __restrict__ ws, int szX, int K,
    unsigned int* __restrict__ cnt)
{
    const int tid = threadIdx.x;
    const int c   = (j << 8) + (int)blockIdx.x;   // 0..2559
    const int kt  = c / 40;
    const int pn  = c - kt * 40;
    const float* src;
    unsigned short* dst;
    if (pn < 8) {
        src = A32 + (size_t)(pn << 8) * K + (kt << 6);
        dst = ws + ((size_t)((pn << 6) + kt) << 14);
    } else {
        src = B32 + (size_t)((pn - 8) << 8) * K + (kt << 6);
        dst = ws + (size_t)szX + ((size_t)(((pn - 8) << 6) + kt) << 14);
    }
    const int row0 = tid >> 3, kg = tid & 7;
    float4 v[8];
#pragma unroll
    for (int p = 0; p < 4; ++p) {
        const float* s = src + (size_t)((p << 6) + row0) * K + (kg << 3);
        v[2 * p]     = *reinterpret_cast<const float4*>(s);
        v[2 * p + 1] = *reinterpret_cast<const float4*>(s + 4);
    }
    // drains cvt loads (and early-retires any staging loads: harmless,
    // KSTEP's counted waits are <=-waits)
    asm volatile("s_waitcnt vmcnt(0)" ::: "memory");
#pragma unroll
    for (int p = 0; p < 4; ++p) {
        u16x8 o;
        o[0] = f2bf(v[2*p].x);   o[1] = f2bf(v[2*p].y);
        o[2] = f2bf(v[2*p].z);   o[3] = f2bf(v[2*p].w);
        o[4] = f2bf(v[2*p+1].x); o[5] = f2bf(v[2*p+1].y);
        o[6] = f2bf(v[2*p+1].z); o[7] = f2bf(v[2*p+1].w);
        *reinterpret_cast<u16x8*>(dst + kg * 2048 + ((p << 6) + row0) * 8) = o;
    }
    __threadfence();   // release: stores drained + visible device-wide
    if (tid == 0)
        __hip_atomic_fetch_add(&cnt[j], 1u, __ATOMIC_RELEASE, __HIP_MEMORY_SCOPE_AGENT);
}

// Wait until all 256 blocks finished round r (rounds are done in-order per
// block, so cnt[r]==256 implies all earlier rounds complete everywhere).
__device__ __forceinline__ void wait_level(int r, unsigned int* cnt) {
    if (threadIdx.x == 0) {
        while (__hip_atomic_load(&cnt[r], __ATOMIC_RELAXED, __HIP_MEMORY_SCOPE_AGENT) < 256u)
            __builtin_amdgcn_s_sleep(2);
        (void)__hip_atomic_load(&cnt[r], __ATOMIC_ACQUIRE, __HIP_MEMORY_SCOPE_AGENT);
    }
    __syncthreads();
}

__global__ __launch_bounds__(512, 1) void persist_cvt_gemm(
    const float* __restrict__ A32,       // x      [M,K]
    const float* __restrict__ B32,       // weight [N,K]
    unsigned short* __restrict__ ws,     // bf16 tiled [szX | szW]
    unsigned int* __restrict__ cnt,      // 16 epoch counters (zeroed)
    float* __restrict__ C,               // out    [M,N]
    int M, int N, int K)
{
    const int NT  = K >> 6;              // 64
    const int szX = M * K;

    __shared__ unsigned short lds[2][2][16384];  // 128 KB GEMM double-buffer

    const int tid = threadIdx.x;

    // ---- startup: rounds 0,1 (levels 0..11 ready after the gate) ----
    cvt_round(0, A32, B32, ws, szX, K, cnt);
    cvt_round(1, A32, B32, ws, szX, K, cnt);
    wait_level(1, cnt);                  // covers staged tiles <= 8 (r(8)=1)

    // ================= GEMM (R14-exact) + interleaved rounds ==============
    const int nbm = M >> 8;              // 8
    const int nbn = N >> 8;              // 32
    const int bid = blockIdx.x;
    const int swzid = (bid & 7) * ((nbm * nbn) >> 3) + (bid >> 3);
    const int bm = swzid % nbm;
    const int bn = swzid / nbm;

    const int wv   = tid >> 6;
    const int lane = tid & 63;
    const int wr   = wv >> 2;
    const int wc   = wv & 3;

    const unsigned short* wsA = ws + (size_t)(bm * NT) * 16384 + wv * 1024 + lane * 8;
    const unsigned short* wsB = ws + (size_t)szX + (size_t)(bn * NT) * 16384 + wv * 1024 + lane * 8;
    const int ldsWOff = wv * 1024;

    const int aBase = (lane >> 4) * 2048 + (wr * 128 + (lane & 15)) * 8;
    const int bBase = (lane >> 4) * 2048 + (wc * 64 + (lane & 15)) * 8;

    f32x4 acc[8][4] = {};

#define STAGE_A(half, tt, ss) do {                                            \
        const unsigned short* s_ = wsA + (size_t)(tt) * 16384 + (half) * 8192;\
        ASYNC16(s_,       &lds[ss][0][(half) * 8192 + ldsWOff]);              \
        ASYNC16(s_ + 512, &lds[ss][0][(half) * 8192 + ldsWOff + 512]);        \
    } while (0)
#define STAGE_B(half, tt, ss) do {                                            \
        const unsigned short* s_ = wsB + (size_t)(tt) * 16384 + (half) * 8192;\
        ASYNC16(s_,       &lds[ss][1][(half) * 8192 + ldsWOff]);              \
        ASYNC16(s_ + 512, &lds[ss][1][(half) * 8192 + ldsWOff + 512]);        \
    } while (0)
#define DSA(ss, ks, fm) (*(const bf16x8*)&lds[ss][0][(ks) * 8192 + aBase + (fm) * 128])
#define DSB(ss, ks, fn) (*(const bf16x8*)&lds[ss][1][(ks) * 8192 + bBase + (fn) * 128])
#define CLUSTER(mh, A0_, A1_, A2_, A3_, B0_, B1_, B2_, B3_) do {              \
        __builtin_amdgcn_s_setprio(1);                                        \
        acc[(mh)*4+0][0] = __builtin_amdgcn_mfma_f32_16x16x32_bf16(A0_, B0_, acc[(mh)*4+0][0], 0, 0, 0); \
        acc[(mh)*4+0][1] = __builtin_amdgcn_mfma_f32_16x16x32_bf16(A0_, B1_, acc[(mh)*4+0][1], 0, 0, 0); \
        acc[(mh)*4+0][2] = __builtin_amdgcn_mfma_f32_16x16x32_bf16(A0_, B2_, acc[(mh)*4+0][2], 0, 0, 0); \
        acc[(mh)*4+0][3] = __builtin_amdgcn_mfma_f32_16x16x32_bf16(A0_, B3_, acc[(mh)*4+0][3], 0, 0, 0); \
        acc[(mh)*4+1][0] = __builtin_amdgcn_mfma_f32_16x16x32_bf16(A1_, B0_, acc[(mh)*4+1][0], 0, 0, 0); \
        acc[(mh)*4+1][1] = __builtin_amdgcn_mfma_f32_16x16x32_bf16(A1_, B1_, acc[(mh)*4+1][1], 0, 0, 0); \
        acc[(mh)*4+1][2] = __builtin_amdgcn_mfma_f32_16x16x32_bf16(A1_, B2_, acc[(mh)*4+1][2], 0, 0, 0); \
        acc[(mh)*4+1][3] = __builtin_amdgcn_mfma_f32_16x16x32_bf16(A1_, B3_, acc[(mh)*4+1][3], 0, 0, 0); \
        acc[(mh)*4+2][0] = __builtin_amdgcn_mfma_f32_16x16x32_bf16(A2_, B0_, acc[(mh)*4+2][0], 0, 0, 0); \
        acc[(mh)*4+2][1] = __builtin_amdgcn_mfma_f32_16x16x32_bf16(A2_, B1_, acc[(mh)*4+2][1], 0, 0, 0); \
        acc[(mh)*4+2][2] = __builtin_amdgcn_mfma_f32_16x16x32_bf16(A2_, B2_, acc[(mh)*4+2][2], 0, 0, 0); \
        acc[(mh)*4+2][3] = __builtin_amdgcn_mfma_f32_16x16x32_bf16(A2_, B3_, acc[(mh)*4+2][3], 0, 0, 0); \
        acc[(mh)*4+3][0] = __builtin_amdgcn_mfma_f32_16x16x32_bf16(A3_, B0_, acc[(mh)*4+3][0], 0, 0, 0); \
        acc[(mh)*4+3][1] = __builtin_amdgcn_mfma_f32_16x16x32_bf16(A3_, B1_, acc[(mh)*4+3][1], 0, 0, 0); \
        acc[(mh)*4+3][2] = __builtin_amdgcn_mfma_f32_16x16x32_bf16(A3_, B2_, acc[(mh)*4+3][2], 0, 0, 0); \
        acc[(mh)*4+3][3] = __builtin_amdgcn_mfma_f32_16x16x32_bf16(A3_, B3_, acc[(mh)*4+3][3], 0, 0, 0); \
        __builtin_amdgcn_s_setprio(0);                                        \
    } while (0)
#define KSTEP(ss, tn) do {                                                    \
        STAGE_A(0, tn, (ss)^1);                                               \
        asm volatile("s_waitcnt vmcnt(2)" ::: "memory");                      \
        __builtin_amdgcn_s_barrier();                                         \
        __builtin_amdgcn_sched_barrier(0);                                    \
        bf16x8 a0 = DSA(ss,0,0), a1 = DSA(ss,0,1), a2 = DSA(ss,0,2), a3 = DSA(ss,0,3); \
        bf16x8 b0 = DSB(ss,0,0), b1 = DSB(ss,0,1), b2 = DSB(ss,0,2), b3 = DSB(ss,0,3); \
        STAGE_B(0, tn, (ss)^1);                                               \
        CLUSTER(0, a0, a1, a2, a3, b0, b1, b2, b3);                           \
        bf16x8 a4 = DSA(ss,0,4), a5 = DSA(ss,0,5), a6 = DSA(ss,0,6), a7 = DSA(ss,0,7); \
        STAGE_A(1, tn, (ss)^1);                                               \
        CLUSTER(1, a4, a5, a6, a7, b0, b1, b2, b3);                           \
        bf16x8 c0 = DSA(ss,1,0), c1 = DSA(ss,1,1), c2 = DSA(ss,1,2), c3 = DSA(ss,1,3); \
        bf16x8 d0 = DSB(ss,1,0), d1 = DSB(ss,1,1), d2 = DSB(ss,1,2), d3 = DSB(ss,1,3); \
        STAGE_B(1, tn, (ss)^1);                                               \
        CLUSTER(0, c0, c1, c2, c3, d0, d1, d2, d3);                           \
        bf16x8 c4 = DSA(ss,1,4), c5 = DSA(ss,1,5), c6 = DSA(ss,1,6), c7 = DSA(ss,1,7); \
        CLUSTER(1, c4, c5, c6, c7, d0, d1, d2, d3);                           \
        __builtin_amdgcn_s_barrier();                                         \
        __builtin_amdgcn_sched_barrier(0);                                    \
    } while (0)

    // prologue: tile 0 -> set 0 (level 0 ready: gate passed)
    STAGE_A(0, 0, 0);
    STAGE_B(0, 0, 0);
    STAGE_A(1, 0, 0);
    STAGE_B(1, 0, 0);

    for (int t = 0; t < NT; t += 2) {
        const int tt = t >> 1;                       // 0..31
        if (tt >= 4 && (tt & 3) == 0) {
            // cover staged tiles through t+8 (next 4 iterations)
            const int lvl = (t + 8 < 63) ? t + 8 : 63;
            wait_level((lvl * 40 + 39) >> 8, cnt);
        }
        if (tt >= 1 && tt <= 4)
            cvt_round(2 * tt, A32, B32, ws, szX, K, cnt);      // rounds 2,4,6,8
        KSTEP(0, t + 1);
        if (tt >= 1 && tt <= 4)
            cvt_round(2 * tt + 1, A32, B32, ws, szX, K, cnt);  // rounds 3,5,7,9
        {
            const int tn2 = (t + 2 < NT) ? t + 2 : NT - 1;     // tail clamp
            KSTEP(1, tn2);
        }
    }

    // ---- epilogue: C/D col = lane&15, row = (lane>>4)*4 + r (m89-verified)
    const int crow0 = bm * 256 + wr * 128 + (lane >> 4) * 4;
    const int ccol0 = bn * 256 + wc * 64 + (lane & 15);
#pragma unroll
    for (int fm = 0; fm < 8; ++fm)
#pragma unroll
        for (int fn = 0; fn < 4; ++fn)
#pragma unroll
            for (int r = 0; r < 4; ++r)
                C[(size_t)(crow0 + fm * 16 + r) * N + (ccol0 + fn * 16)] = acc[fm][fn][r];

#undef STAGE_A
#undef STAGE_B
#undef DSA
#undef DSB
#undef CLUSTER
#undef KSTEP
}

// ---------------- fallback (shape mismatch only; never taken at 2048x8192x4096) ----------------
__device__ inline int lds_off(int row, int slot) {
    return row * 32 + (((slot ^ ((row >> 1) & 3)) & 3) << 3);
}

__global__ __launch_bounds__(256) void gemm_bt_fused(
    const float* __restrict__ A, const float* __restrict__ B,
    float* __restrict__ C, int M, int N, int K)
{
    constexpr int BM = 128, BN = 128, BK = 32;
    __shared__ unsigned short sA[2][BM * BK];
    __shared__ unsigned short sB[2][BN * BK];

    const int nbm = M / BM, nbn = N / BN;
    const int nwg = nbm * nbn;
    const int bid = blockIdx.x;
    int swz = bid;
    if ((nwg & 7) == 0) { const int q = nwg >> 3; swz = (bid & 7) * q + (bid >> 3); }
    const int bm = swz % nbm, bn = swz / nbm;

    const int tid = threadIdx.x;
    const int srow = tid >> 1;
    const int scol = (tid & 1) * 16;
    const float* gA = A + (size_t)(bm * BM + srow) * K + scol;
    const float* gB = B + (size_t)(bn * BN + srow) * K + scol;
    const int s0  = (tid & 1) * 2;
    const int wo0 = lds_off(srow, s0);
    const int wo1 = lds_off(srow, s0 + 1);

    const int wave = tid >> 6, lane = tid & 63;
    const int wr = wave >> 1, wc = wave & 1;
    const int fr = lane & 15;
    const int slr = lane >> 4;
    int offA[4], offB[4];
#pragma unroll
    for (int i = 0; i < 4; ++i) {
        offA[i] = lds_off(wr * 64 + i * 16 + fr, slr);
        offB[i] = lds_off(wc * 64 + i * 16 + fr, slr);
    }

    f32x4 acc[4][4] = {};
    const int NT = K / BK;

    float4 va[4], vb[4];
#pragma unroll
    for (int p = 0; p < 4; ++p) {
        va[p] = *reinterpret_cast<const float4*>(gA + p * 4);
        vb[p] = *reinterpret_cast<const float4*>(gB + p * 4);
    }

    for (int t = 0; t < NT; ++t) {
        const int cur = t & 1;
        u16x8 pa0, pa1, pb0, pb1;
#pragma unroll
        for (int e = 0; e < 4; ++e) {
            pa0[e] = f2bf(va[0][e]);  pa0[4 + e] = f2bf(va[1][e]);
            pa1[e] = f2bf(va[2][e]);  pa1[4 + e] = f2bf(va[3][e]);
            pb0[e] = f2bf(vb[0][e]);  pb0[4 + e] = f2bf(vb[1][e]);
            pb1[e] = f2bf(vb[2][e]);  pb1[4 + e] = f2bf(vb[3][e]);
        }
        *reinterpret_cast<u16x8*>(&sA[cur][wo0]) = pa0;
        *reinterpret_cast<u16x8*>(&sA[cur][wo1]) = pa1;
        *reinterpret_cast<u16x8*>(&sB[cur][wo0]) = pb0;
        *reinterpret_cast<u16x8*>(&sB[cur][wo1]) = pb1;

        const int kn = (t + 1 < NT) ? (t + 1) * BK : t * BK;
#pragma unroll
        for (int p = 0; p < 4; ++p) {
            va[p] = *reinterpret_cast<const float4*>(gA + kn + p * 4);
            vb[p] = *reinterpret_cast<const float4*>(gB + kn + p * 4);
        }

        __syncthreads();

        bf16x8 a[4], b[4];
#pragma unroll
        for (int i = 0; i < 4; ++i) a[i] = *reinterpret_cast<const bf16x8*>(&sA[cur][offA[i]]);
#pragma unroll
        for (int j = 0; j < 4; ++j) b[j] = *reinterpret_cast<const bf16x8*>(&sB[cur][offB[j]]);
#pragma unroll
        for (int i = 0; i < 4; ++i)
#pragma unroll
            for (int j = 0; j < 4; ++j)
                acc[i][j] = __builtin_amdgcn_mfma_f32_16x16x32_bf16(a[i], b[j], acc[i][j], 0, 0, 0);
    }

    const int crow0 = bm * BM + wr * 64 + (lane >> 4) * 4;
    const int ccol0 = bn * BN + wc * 64 + fr;
#pragma unroll
    for (int i = 0; i < 4; ++i)
#pragma unroll
        for (int j = 0; j < 4; ++j)
#pragma unroll
            for (int r = 0; r < 4; ++r)
                C[(size_t)(crow0 + i * 16 + r) * N + (ccol0 + j * 16)] = acc[i][j][r];
}

extern "C" void kernel_launch(void* const* d_in, const int* in_sizes, int n_in,
                              void* d_out, int out_size, void* d_ws, size_t ws_size,
                              hipStream_t stream) {
    int K = 4096;
    int M = in_sizes[0] / K;   // 2048
    int N = in_sizes[1] / K;   // 8192

    const float* x = (const float*)d_in[0];
    const float* w = (const float*)d_in[1];
    float* out     = (float*)d_out;
    unsigned short* wsp = (unsigned short*)d_ws;

    const size_t szX = (size_t)in_sizes[0], szW = (size_t)in_sizes[1];
    const size_t cntOff = (((szX + szW) * 2) + 255) & ~(size_t)255;
    const size_t need = cntOff + 256;
    unsigned int* cnt = (unsigned int*)((char*)d_ws + cntOff);

    // Pure-arithmetic selection (R14 lesson), EXACT-shape guard: the round
    // schedule constants (10 rounds, 40 panels, 256 blocks) assume this shape.
    const bool pers_ok = (M == 2048) && (N == 8192) && (K == 4096) &&
                         (ws_size >= need);

    if (pers_ok) {
        reset_cnt16<<<dim3(1), dim3(1), 0, stream>>>(cnt);
        persist_cvt_gemm<<<dim3(256), dim3(512), 0, stream>>>(x, w, wsp, cnt, out, M, N, K);
        return;
    }
    const int nwg = (M / 128) * (N / 128);
    gemm_bt_fused<<<dim3(nwg), dim3(256), 0, stream>>>(x, w, out, M, N, K);
}